// Round 1
// 212.063 us; speedup vs baseline: 1.0231x; 1.0231x over previous
//
#include <hip/hip_runtime.h>

#define BATCH 64
#define T 480000
#define T4 (T / 4)                     // 120000 float4 chunks per row
#define NTAPS 16
#define TILE 512                       // output chunks per block
#define SEGS 9                         // 9 x 64-chunk global_load_lds segments = 576 chunks
#define LDSC 576                       // LDS chunks: 4 halo + 512 tile + 60 overread
#define TPR ((T4 + TILE - 1) / TILE)   // 235 tiles per row (last tile: 192 valid chunks)

typedef float floatx4 __attribute__((ext_vector_type(4)));

__global__ __launch_bounds__(256) void fir_tile_kernel(
    const float* __restrict__ x,
    const float* __restrict__ b,
    float* __restrict__ y)
{
    // 9216 B LDS -> 8 blocks/CU resident (capped by 32 waves/CU), block-level
    // latency hiding: while one block waits at its barrier, 7 others compute.
    __shared__ floatx4 lds4[LDSC];

    const int tid  = threadIdx.x;
    const int lane = tid & 63;
    const int wave = tid >> 6;

    const int bid = blockIdx.x;
    const int r   = bid / TPR;         // batch row (SALU magic-div)
    const int t   = bid - r * TPR;     // tile within row; consecutive blocks share halo lines

    const int    base_c = t * TILE - 4;          // row-chunk index of LDS slot 0
    const float* xrow   = x + (size_t)r * T;

    // ---- Stage 576 chunks straight into LDS (no VGPR round trip).
    // Wave w loads segments w, w+4[, 8]; LDS dest is wave-uniform base + lane*16
    // (layout is linear, exactly what global_load_lds requires). Per-lane global
    // address clamped at row edges (left garbage fixed below; right overread
    // feeds only predicated-off outputs).
    for (int seg = wave; seg < SEGS; seg += 4) {
        int c = base_c + seg * 64 + lane;
        c = c < 0 ? 0 : c;
        c = c > T4 - 1 ? T4 - 1 : c;
        const float* gp = xrow + (size_t)c * 4;
        __builtin_amdgcn_global_load_lds(
            (const __attribute__((address_space(1))) void*)gp,
            (__attribute__((address_space(3))) void*)((char*)&lds4[0] + seg * 1024),
            16, 0, 0);
    }

    // Taps: wave-uniform address + literal indices -> s_loads, live in SGPRs.
    float tap[NTAPS];
#pragma unroll
    for (int k = 0; k < NTAPS; ++k) tap[k] = b[k];

    __syncthreads();   // compiler drains vmcnt(0) before s_barrier -> LDS tile valid

    if (t == 0) {      // row start: zero-initialized shift register == x[t<0] = 0
        if (tid < 4) lds4[tid] = (floatx4){0.f, 0.f, 0.f, 0.f};
        __syncthreads();
    }

    floatx4* yv = (floatx4*)y + (size_t)r * T4;

#pragma unroll
    for (int p = 0; p < 2; ++p) {
        const int j  = tid + 256 * p;  // output chunk within tile
        const int jo = j + 4;          // own chunk's LDS slot

        // 5 x ds_read_b128, lane stride 16 B -> conflict-free (2-way is free).
        float s[20];
#pragma unroll
        for (int m = 0; m < 5; ++m) {
            floatx4 v = lds4[jo - 4 + m];
            s[4 * m + 0] = v.x;
            s[4 * m + 1] = v.y;
            s[4 * m + 2] = v.z;
            s[4 * m + 3] = v.w;
        }

        floatx4 out;
#pragma unroll
        for (int q = 0; q < 4; ++q) {
            float a = 0.f;
#pragma unroll
            for (int k = 0; k < NTAPS; ++k) a += tap[k] * s[16 + q - k];
            out[q] = a;
        }

        // Coalesced nontemporal store: full lines, keeps y out of LLC so x stays hot.
        const int oc = t * TILE + j;
        if (oc < T4) __builtin_nontemporal_store(out, yv + oc);
    }
}

extern "C" void kernel_launch(void* const* d_in, const int* in_sizes, int n_in,
                              void* d_out, int out_size, void* d_ws, size_t ws_size,
                              hipStream_t stream)
{
    const float* x = (const float*)d_in[0];
    const float* b = (const float*)d_in[1];
    float* y = (float*)d_out;

    fir_tile_kernel<<<BATCH * TPR, 256, 0, stream>>>(x, b, y);
}